// Round 1
// baseline (181.455 us; speedup 1.0000x reference)
//
#include <hip/hip_runtime.h>

// NRI MLP decoder, fused f16-MFMA pipeline, v17.
// B=4, T=64 (t<63 out), A=32, R=992 (=32 recv x 31 edges), D=64, S=4,
// E=4 (type 0 skipped), MH=MO=NH=256.
//
//   h1[b,t,r] = lrelu(PS[send(r)] + PRb[rec(r)])   (PRb has b1 folded, from ka)
//   msg = lrelu(h1 @ W2 + b2) ; agg[a] = sum_{r:rec=a} g[r]*msg[r]
// kb v17: W2F[e] (128KB) is made FULLY LDS-RESIDENT (gfx950 has 160KB LDS);
// one block per (e,bt) persists over all 8 M-chunks (q). Main loop has zero
// global->LDS staging and zero vmcnt drains: barriers are lgkmcnt-only and
// protect only the 8KB h1 double-buffer. h1-build P loads issue before the
// MFMA cluster and are consumed after it (latency hidden under MFMA); h1
// writes are lane-linear (wave w builds tile w) -> conflict-free. Build-ahead
// across items (step 7 builds next item's step 0) keeps the pipeline full.

typedef _Float16 f16x8 __attribute__((ext_vector_type(8)));
typedef float f32x4 __attribute__((ext_vector_type(4)));

#define MFMAH(a, b, c) __builtin_amdgcn_mfma_f32_16x16x32_f16((a), (b), (c), 0, 0, 0)

// full-drain barrier (__syncthreads semantics, explicit) — prologue only
#define KBAR0() do {                                             \
  __builtin_amdgcn_sched_barrier(0);                             \
  asm volatile("s_waitcnt vmcnt(0) lgkmcnt(0)" ::: "memory");    \
  __builtin_amdgcn_s_barrier();                                  \
  __builtin_amdgcn_sched_barrier(0);                             \
} while (0)

// LDS-only barrier: drains ds ops, leaves global loads in flight
#define KBARL() do {                                             \
  __builtin_amdgcn_sched_barrier(0);                             \
  asm volatile("s_waitcnt lgkmcnt(0)" ::: "memory");             \
  __builtin_amdgcn_s_barrier();                                  \
  __builtin_amdgcn_sched_barrier(0);                             \
} while (0)

__device__ __forceinline__ unsigned pkh(float lo, float hi) {
  auto h = __builtin_amdgcn_cvt_pkrtz(lo, hi);
  return __builtin_bit_cast(unsigned, h);
}
__device__ __forceinline__ unsigned short f2h(float f) {
  return __builtin_bit_cast(unsigned short, (_Float16)f);
}
__device__ __forceinline__ float lrelu(float x) { return x > 0.f ? x : 0.01f * x; }

__device__ __forceinline__ void gl16(const void* g, void* l) {
  __builtin_amdgcn_global_load_lds(
      (const __attribute__((address_space(1))) unsigned int*)(unsigned long long)g,
      (__attribute__((address_space(3))) unsigned int*)(unsigned int)(unsigned long long)l,
      16, 0, 0);
}

// ---------------- kernel W: weight transpose + f16 convert ----------------
// W2F fragment-linear: [e][kstep 0..7][ntile 0..15][lane 0..63][j 0..7]
//   n = ntile*16 + (lane&15), k = kstep*32 + (lane>>4)*8 + j.
__global__ __launch_bounds__(256) void kw(
    const float* __restrict__ w1, const float* __restrict__ w2,
    const float* __restrict__ o1, const float* __restrict__ o2, const float* __restrict__ o3,
    unsigned short* __restrict__ W1T, unsigned short* __restrict__ W2F,
    unsigned short* __restrict__ O1T, unsigned short* __restrict__ O2T,
    unsigned short* __restrict__ O3T) {
  int i = blockIdx.x * 256 + threadIdx.x;
  if (i < 98304) {
    int k = i & 63, n = (i >> 6) & 255, eh = i >> 14;
    int e = (eh >> 1) + 1, half = eh & 1;
    W1T[i] = f2h(w1[(e * 128 + half * 64 + k) * 256 + n]);
    return;
  }
  i -= 98304;
  if (i < 196608) {
    int j = i & 7, l = (i >> 3) & 63, t = (i >> 9) & 15, s = (i >> 13) & 7, e = i >> 16;
    int n = t * 16 + (l & 15);
    int k = s * 32 + (l >> 4) * 8 + j;
    W2F[i] = f2h(w2[(e + 1) * 65536 + k * 256 + n]);
    return;
  }
  i -= 196608;
  if (i < 81920) {
    int k = i % 320, n = i / 320;
    O1T[i] = f2h(o1[k * 256 + n]);
    return;
  }
  i -= 81920;
  if (i < 65536) {
    int k = i & 255, n = i >> 8;
    O2T[i] = f2h(o2[k * 256 + n]);
    return;
  }
  i -= 65536;
  {
    int k = i & 255, n = i >> 8;
    O3T[i] = f2h(o3[k * 64 + n]);
  }
}

// ---------------- kernel A: per-atom projections P + gates G ----------------
__global__ __launch_bounds__(256) void ka(
    const float* __restrict__ inputs, const float* __restrict__ state,
    const float* __restrict__ rel_type, const unsigned short* __restrict__ W1T,
    const float* __restrict__ b1g,
    unsigned short* __restrict__ P, float* __restrict__ G) {
  int t = blockIdx.x, b = blockIdx.y;
  int bt = b * 63 + t;
  int tid = threadIdx.x, lane = tid & 63, wid = tid >> 6;
  int waveM = wid & 1, waveN = wid >> 1;
  __shared__ __align__(16) _Float16 xa[32 * 72];
  __shared__ __align__(16) _Float16 Bt[256 * 72];
  __shared__ __align__(16) _Float16 Ps[32 * 256];
  __shared__ float ss[32][4];
  {
    int a = tid >> 3, d0 = (tid & 7) * 8;
    const float* src = inputs + (((b * 32 + a) * 64 + t) << 6) + d0;
    float4 v0 = *(const float4*)src;
    float4 v1 = *(const float4*)(src + 4);
    uint4 w;
    w.x = pkh(v0.x, v0.y); w.y = pkh(v0.z, v0.w);
    w.z = pkh(v1.x, v1.y); w.w = pkh(v1.z, v1.w);
    *(uint4*)&xa[a * 72 + d0] = w;
  }
  if (tid < 128) {
    int a = tid >> 2, s = tid & 3;
    ss[a][s] = state[((b * 32 + a) * 64 + t) * 4 + s];
  }
  __syncthreads();
  #pragma unroll
  for (int q = 0; q < 12; ++q) {
    int task = tid + q * 256;
    int e = task >> 10, rem = task & 1023, a = rem >> 5, k = rem & 31;
    float g = 0.f;
    if (k < 31) {
      int sA = k + (k >= a ? 1 : 0);
      int r = a * 31 + k;
      const float* rt = rel_type + (b * 992 + r) * 16 + (e + 1);
      g = rt[0] * ss[sA][0] + rt[4] * ss[sA][1] + rt[8] * ss[sA][2] + rt[12] * ss[sA][3];
    }
    G[(bt * 3 + e) * 1024 + a * 32 + k] = g;
  }
  for (int eh = 0; eh < 6; ++eh) {
    #pragma unroll
    for (int q = 0; q < 8; ++q) {
      int cid = tid + q * 256;
      int n = cid >> 3, c8 = (cid & 7) * 8;
      *(uint4*)&Bt[n * 72 + c8] = *(const uint4*)&W1T[(eh * 256 + n) * 64 + c8];
    }
    __syncthreads();
    f32x4 acc[8];
    #pragma unroll
    for (int f = 0; f < 8; ++f) acc[f] = f32x4{0.f, 0.f, 0.f, 0.f};
    #pragma unroll
    for (int ik = 0; ik < 2; ++ik) {
      int k0 = ik * 32;
      f16x8 av = *(const f16x8*)&xa[(waveM * 16 + (lane & 15)) * 72 + k0 + (lane >> 4) * 8];
      #pragma unroll
      for (int f = 0; f < 8; ++f) {
        f16x8 bv = *(const f16x8*)&Bt[(waveN * 128 + f * 16 + (lane & 15)) * 72 + k0 + (lane >> 4) * 8];
        acc[f] = MFMAH(av, bv, acc[f]);
      }
    }
    #pragma unroll
    for (int f = 0; f < 8; ++f) {
      int c = waveN * 128 + f * 16 + (lane & 15);
      float bias = (eh & 1) ? b1g[((eh >> 1) + 1) * 256 + c] : 0.f;
      #pragma unroll
      for (int i = 0; i < 4; ++i) {
        int rrow = waveM * 16 + (lane >> 4) * 4 + i;
        Ps[rrow * 256 + c] = (_Float16)(acc[f][i] + bias);
      }
    }
    __syncthreads();
    unsigned short* dst = P + (bt * 6 + eh) * 8192;
    #pragma unroll
    for (int q = 0; q < 4; ++q) {
      int o = (tid + q * 256) * 8;
      *(uint4*)&dst[o] = *(const uint4*)&Ps[o];
    }
    __syncthreads();
  }
}

// ---------------- kernel B v17: resident W2, persistent (e,bt) block --------
// grid.x = 756 = 3*252; block handles all 8 q-chunks of one (e,bt).
__global__ __launch_bounds__(512, 2) void kb(
    const unsigned short* __restrict__ P, const float* __restrict__ G,
    const unsigned short* __restrict__ W2F, const float* __restrict__ b2g,
    unsigned short* __restrict__ AGG3) {
  int bx = blockIdx.x;
  int e = bx / 252;
  int bt = bx - e * 252;
  int tid = threadIdx.x, lane = tid & 63, wid = tid >> 6;
  int waveM = wid & 1, waveN = wid >> 1;   // 2M x 4N
  int lane15 = lane & 15, kqh = lane >> 4; // 0..3

  __shared__ __align__(16) _Float16 Bt[65536];    // 128KB: full W2F[e], frag-linear
  __shared__ __align__(16) _Float16 h1F[2][4096]; // 16KB dbuf, frag-linear
  __shared__ float gs[1024];
  __shared__ float b2s[256];
  // LDS total: 131072 + 16384 + 4096 + 1024 = 152576B -> 1 block/CU.

  const unsigned short* psrc  = P + (bt * 6 + e * 2) * 8192;  // PS slab (send)
  const unsigned short* prsrc = psrc + 8192;                   // PRb slab
  const unsigned short* w2f   = W2F + e * 65536;               // [step][ntile][lane][8]

  // ---- prologue: resident B, gates, biases, first h1 tile ----
  #pragma unroll
  for (int j = 0; j < 16; ++j) {
    int c = j * 512 + tid;
    gl16(w2f + c * 8, (char*)&Bt[0] + c * 16);
  }
  int gofs = (bt * 3 + e) << 10;
  gs[tid] = G[gofs + tid];
  gs[512 + tid] = G[gofs + 512 + tid];
  if (tid < 256) b2s[tid] = b2g[(e + 1) * 256 + tid];

  // wave w builds h1 tile w: lane l -> row w*16+(l&15), k-chunk (l>>4)*8.
  int rrow = wid * 16 + lane15;
  int al0 = rrow >> 5, bk = rrow & 31;  // al0 = wid>>1 (atom within item), bk = edge slot
  {
    int bs = (bk < 31) ? bk + (bk >= al0 ? 1 : 0) : 0;  // item 0: a0n = 0
    int ko = kqh * 8;
    f16x8 h = *(const f16x8*)(psrc + bs * 256 + ko) + *(const f16x8*)(prsrc + al0 * 256 + ko);
    *(f16x8*)&h1F[0][wid * 512 + lane * 8] = __builtin_elementwise_max(h, h * (_Float16)0.01f);
  }
  KBAR0();  // B resident + gs/b2s + h1(0,0) ready

  f32x4 acc[4][4];
  _Float16* aggh = (_Float16*)AGG3;

  for (int it = 0; it < 8; ++it) {
    int a0 = it * 4;
    #pragma unroll
    for (int f = 0; f < 4; ++f)
      #pragma unroll
      for (int g2 = 0; g2 < 4; ++g2) acc[f][g2] = f32x4{0.f, 0.f, 0.f, 0.f};

    #pragma unroll
    for (int s = 0; s < 8; ++s) {
      int buf = s & 1;
      bool hasNext = (s < 7) || (it < 7);
      // T14 split: issue next h1-tile P loads BEFORE the MFMA cluster...
      f16x8 pv, rv;
      if (hasNext) {
        int a0n = (s < 7) ? a0 : a0 + 4;   // step 7 builds next item's step 0
        int sn = (s < 7) ? s + 1 : 0;
        int bs = (bk < 31) ? bk + (bk >= a0n + al0 ? 1 : 0) : 0;
        int ko = sn * 32 + kqh * 8;
        pv = *(const f16x8*)(psrc + bs * 256 + ko);
        rv = *(const f16x8*)(prsrc + (a0n + al0) * 256 + ko);
      }
      // MFMA on h1F[buf] x resident Bt — no vmem dependency, no vmcnt wait
      f16x8 af[4];
      #pragma unroll
      for (int f = 0; f < 4; ++f)
        af[f] = *(const f16x8*)&h1F[buf][(waveM * 4 + f) * 512 + lane * 8];
      __builtin_amdgcn_s_setprio(1);
      #pragma unroll
      for (int g2 = 0; g2 < 4; ++g2) {
        f16x8 bv = *(const f16x8*)&Bt[(s * 16 + waveN * 4 + g2) * 512 + lane * 8];
        #pragma unroll
        for (int f = 0; f < 4; ++f)
          acc[f][g2] = MFMAH(af[f], bv, acc[f][g2]);
      }
      __builtin_amdgcn_s_setprio(0);
      // ...and consume them AFTER it (latency hidden under ~660cy of MFMA)
      if (hasNext) {
        f16x8 h = pv + rv;
        *(f16x8*)&h1F[buf ^ 1][wid * 512 + lane * 8] =
            __builtin_elementwise_max(h, h * (_Float16)0.01f);
      }
      if (s < 7) KBARL();  // lgkm-only: h1 dbuf handoff, globals stay in flight
    }

    // epilogue: p(al,c) = sum_k g[k]*lrelu(acc+b2); write f16 partial per type
    #pragma unroll
    for (int half = 0; half < 2; ++half) {
      int al = waveM * 2 + half;
      #pragma unroll
      for (int g2 = 0; g2 < 4; ++g2) {
        int c = waveN * 64 + g2 * 16 + lane15;
        float bb = b2s[c];
        float p = 0.f;
        #pragma unroll
        for (int fh = 0; fh < 2; ++fh) {
          int f = half * 2 + fh;
          int k4 = fh * 16 + kqh * 4;
          #pragma unroll
          for (int i = 0; i < 4; ++i)
            p += gs[(a0 + al) * 32 + k4 + i] * lrelu(acc[f][g2][i] + bb);
        }
        p += __shfl_xor(p, 16, 64);
        p += __shfl_xor(p, 32, 64);
        if (lane < 16)
          aggh[(size_t)e * 2064384 + (((bt * 32 + a0 + al) << 8) + c)] = (_Float16)p;
      }
    }
    if (it < 7) KBARL();  // h1F[0] (next item, built at s==7) now visible
  }
}

// ---------------- kernel C: output MLP 320->256->256->64 + residual ----------------
__global__ __launch_bounds__(256) void kc(
    const float* __restrict__ inputs, const unsigned short* __restrict__ AGG3,
    const unsigned short* __restrict__ O1T, const unsigned short* __restrict__ O2T,
    const unsigned short* __restrict__ O3T,
    const float* __restrict__ ob1, const float* __restrict__ ob2, const float* __restrict__ ob3,
    float* __restrict__ out) {
  int t = blockIdx.x, b = blockIdx.y;
  int bt = b * 63 + t;
  int tid = threadIdx.x, lane = tid & 63, wid = tid >> 6;
  int waveM = wid & 1, waveN = wid >> 1;
  __shared__ __align__(16) _Float16 aug[32 * 328];
  __shared__ __align__(16) _Float16 h1[32 * 264];
  __shared__ __align__(16) _Float16 h2[32 * 264];
  __shared__ __align__(16) _Float16 Bt[256 * 40];
  __shared__ __align__(16) float xs[32 * 64];
  __shared__ float lb1[256], lb2[256], lb3[64];
  {
    int a = tid >> 3, d0 = (tid & 7) * 8;
    const float* src = inputs + (((b * 32 + a) * 64 + t) << 6) + d0;
    float4 v0 = *(const float4*)src;
    float4 v1 = *(const float4*)(src + 4);
    *(float4*)&xs[a * 64 + d0] = v0;
    *(float4*)&xs[a * 64 + d0 + 4] = v1;
    uint4 w;
    w.x = pkh(v0.x, v0.y); w.y = pkh(v0.z, v0.w);
    w.z = pkh(v1.x, v1.y); w.w = pkh(v1.z, v1.w);
    *(uint4*)&aug[a * 328 + d0] = w;
  }
  #pragma unroll
  for (int qq = 0; qq < 4; ++qq) {
    int cid = tid + qq * 256;
    int a = cid >> 5, c8 = (cid & 31) * 8;
    size_t o = ((size_t)(bt * 32 + a) << 8) + c8;
    f16x8 v0 = *(const f16x8*)&AGG3[o];
    f16x8 v1 = *(const f16x8*)&AGG3[2064384 + o];
    f16x8 v2 = *(const f16x8*)&AGG3[4128768 + o];
    f16x8 s = v0 + v1 + v2;
    *(uint4*)&aug[a * 328 + 64 + c8] = __builtin_bit_cast(uint4, s);
  }
  lb1[tid] = ob1[tid];
  lb2[tid] = ob2[tid];
  if (tid < 64) lb3[tid] = ob3[tid];
  __syncthreads();
  f32x4 acc[8];
  #pragma unroll
  for (int f = 0; f < 8; ++f) acc[f] = f32x4{0.f, 0.f, 0.f, 0.f};
  for (int kk = 0; kk < 10; ++kk) {  // fc1: K=320
    #pragma unroll
    for (int q = 0; q < 4; ++q) {
      int cid = tid + q * 256;
      int n = cid >> 2, c8 = (cid & 3) * 8;
      *(uint4*)&Bt[n * 40 + c8] = *(const uint4*)&O1T[n * 320 + kk * 32 + c8];
    }
    __syncthreads();
    f16x8 av = *(const f16x8*)&aug[(waveM * 16 + (lane & 15)) * 328 + kk * 32 + (lane >> 4) * 8];
    #pragma unroll
    for (int f = 0; f < 8; ++f) {
      f16x8 bv = *(const f16x8*)&Bt[(waveN * 128 + f * 16 + (lane & 15)) * 40 + (lane >> 4) * 8];
      acc[f] = MFMAH(av, bv, acc[f]);
    }
    __syncthreads();
  }
  #pragma unroll
  for (int f = 0; f < 8; ++f) {
    int c = waveN * 128 + f * 16 + (lane & 15);
    #pragma unroll
    for (int i = 0; i < 4; ++i) {
      int r = waveM * 16 + (lane >> 4) * 4 + i;
      h1[r * 264 + c] = (_Float16)lrelu(acc[f][i] + lb1[c]);
    }
  }
  __syncthreads();
  #pragma unroll
  for (int f = 0; f < 8; ++f) acc[f] = f32x4{0.f, 0.f, 0.f, 0.f};
  for (int kk = 0; kk < 8; ++kk) {  // fc2: K=256
    #pragma unroll
    for (int q = 0; q < 4; ++q) {
      int cid = tid + q * 256;
      int n = cid >> 2, c8 = (cid & 3) * 8;
      *(uint4*)&Bt[n * 40 + c8] = *(const uint4*)&O2T[n * 256 + kk * 32 + c8];
    }
    __syncthreads();
    f16x8 av = *(const f16x8*)&h1[(waveM * 16 + (lane & 15)) * 264 + kk * 32 + (lane >> 4) * 8];
    #pragma unroll
    for (int f = 0; f < 8; ++f) {
      f16x8 bv = *(const f16x8*)&Bt[(waveN * 128 + f * 16 + (lane & 15)) * 40 + (lane >> 4) * 8];
      acc[f] = MFMAH(av, bv, acc[f]);
    }
    __syncthreads();
  }
  #pragma unroll
  for (int f = 0; f < 8; ++f) {
    int c = waveN * 128 + f * 16 + (lane & 15);
    #pragma unroll
    for (int i = 0; i < 4; ++i) {
      int r = waveM * 16 + (lane >> 4) * 4 + i;
      h2[r * 264 + c] = (_Float16)lrelu(acc[f][i] + lb2[c]);
    }
  }
  __syncthreads();
  f32x4 a3[2];
  a3[0] = f32x4{0.f, 0.f, 0.f, 0.f};
  a3[1] = f32x4{0.f, 0.f, 0.f, 0.f};
  for (int kk = 0; kk < 8; ++kk) {  // fc3: K=256, N=64
    {
      int n = tid >> 2, c8 = (tid & 3) * 8;
      *(uint4*)&Bt[n * 40 + c8] = *(const uint4*)&O3T[n * 256 + kk * 32 + c8];
    }
    __syncthreads();
    f16x8 av = *(const f16x8*)&h2[(waveM * 16 + (lane & 15)) * 264 + kk * 32 + (lane >> 4) * 8];
    #pragma unroll
    for (int f = 0; f < 2; ++f) {
      f16x8 bv = *(const f16x8*)&Bt[(waveN * 32 + f * 16 + (lane & 15)) * 40 + (lane >> 4) * 8];
      a3[f] = MFMAH(av, bv, a3[f]);
    }
    __syncthreads();
  }
  #pragma unroll
  for (int f = 0; f < 2; ++f) {
    int d = waveN * 32 + f * 16 + (lane & 15);
    #pragma unroll
    for (int i = 0; i < 4; ++i) {
      int a = waveM * 16 + (lane >> 4) * 4 + i;
      out[((b * 32 + a) * 63 + t) * 64 + d] = a3[f][i] + lb3[d] + xs[a * 64 + d];
    }
  }
}

extern "C" void kernel_launch(void* const* d_in, const int* in_sizes, int n_in,
                              void* d_out, int out_size, void* d_ws, size_t ws_size,
                              hipStream_t stream) {
  const float* inputs   = (const float*)d_in[0];
  const float* state    = (const float*)d_in[1];
  const float* rel_type = (const float*)d_in[2];
  const float* w1  = (const float*)d_in[5];
  const float* b1  = (const float*)d_in[6];
  const float* w2  = (const float*)d_in[7];
  const float* b2  = (const float*)d_in[8];
  const float* o1w = (const float*)d_in[9];
  const float* o1b = (const float*)d_in[10];
  const float* o2w = (const float*)d_in[11];
  const float* o2b = (const float*)d_in[12];
  const float* o3w = (const float*)d_in[13];
  const float* o3b = (const float*)d_in[14];
  char* ws = (char*)d_ws;
  unsigned short* W1T = (unsigned short*)(ws + 0);
  unsigned short* W2F = (unsigned short*)(ws + 196608);     // 393216 B (frag-linear)
  unsigned short* O1T = (unsigned short*)(ws + 589824);
  unsigned short* O2T = (unsigned short*)(ws + 753664);
  unsigned short* O3T = (unsigned short*)(ws + 884736);
  unsigned short* Pp  = (unsigned short*)(ws + 917504);     // 24772608 B
  float* G    = (float*)(ws + 25690112);                    // 3096576 B
  unsigned short* AGG3 = (unsigned short*)(ws + 28786688);  // 12386304 B
  float* out = (float*)d_out;

  kw<<<1792, 256, 0, stream>>>(w1, w2, o1w, o2w, o3w, W1T, W2F, O1T, O2T, O3T);
  ka<<<dim3(63, 4), 256, 0, stream>>>(inputs, state, rel_type, W1T, b1, Pp, G);
  kb<<<756, 512, 0, stream>>>(Pp, G, W2F, b2, AGG3);
  kc<<<dim3(63, 4), 256, 0, stream>>>(inputs, AGG3, O1T, O2T, O3T, o1b, o2b, o3b, out);
}

// Round 2
// 164.965 us; speedup vs baseline: 1.1000x; 1.1000x over previous
//
#include <hip/hip_runtime.h>

// NRI MLP decoder, fused f16-MFMA pipeline, v18.
// B=4, T=64 (t<63 out), A=32, R=992 (=32 recv x 31 edges), D=64, S=4,
// E=4 (type 0 skipped), MH=MO=NH=256.
//
//   h1[b,t,r] = lrelu(PS[send(r)] + PRb[rec(r)])   (PRb has b1 folded, from ka)
//   msg = lrelu(h1 @ W2 + b2) ; agg[a] = sum_{r:rec=a} g[r]*msg[r]
// kb v18 = v16 schedule skeleton + v17 conflict-free build/write mappings +
// 3-slot Bt ring with COUNTED vmcnt (stage s+2 at step s; barrier waits
// vmcnt(2), never 0, leaving the newest stage in flight with a full step of
// slack) + lgkm-only barriers. LDS 67KB -> 2 blocks/CU; launch_bounds(512,4)
// caps VGPR at 128 so 16 waves/CU are realizable (v17's 1-block/CU lockstep
// was the regression mechanism).

typedef _Float16 f16x8 __attribute__((ext_vector_type(8)));
typedef float f32x4 __attribute__((ext_vector_type(4)));

#define MFMAH(a, b, c) __builtin_amdgcn_mfma_f32_16x16x32_f16((a), (b), (c), 0, 0, 0)

// full-drain barrier (__syncthreads semantics, explicit) — prologue only
#define KBAR0() do {                                             \
  __builtin_amdgcn_sched_barrier(0);                             \
  asm volatile("s_waitcnt vmcnt(0) lgkmcnt(0)" ::: "memory");    \
  __builtin_amdgcn_s_barrier();                                  \
  __builtin_amdgcn_sched_barrier(0);                             \
} while (0)

// LDS-only barrier: drains ds ops, leaves global loads in flight
#define KBARL() do {                                             \
  __builtin_amdgcn_sched_barrier(0);                             \
  asm volatile("s_waitcnt lgkmcnt(0)" ::: "memory");             \
  __builtin_amdgcn_s_barrier();                                  \
  __builtin_amdgcn_sched_barrier(0);                             \
} while (0)

__device__ __forceinline__ unsigned pkh(float lo, float hi) {
  auto h = __builtin_amdgcn_cvt_pkrtz(lo, hi);
  return __builtin_bit_cast(unsigned, h);
}
__device__ __forceinline__ unsigned short f2h(float f) {
  return __builtin_bit_cast(unsigned short, (_Float16)f);
}
__device__ __forceinline__ float lrelu(float x) { return x > 0.f ? x : 0.01f * x; }

__device__ __forceinline__ void gl16(const void* g, void* l) {
  __builtin_amdgcn_global_load_lds(
      (const __attribute__((address_space(1))) unsigned int*)(unsigned long long)g,
      (__attribute__((address_space(3))) unsigned int*)(unsigned int)(unsigned long long)l,
      16, 0, 0);
}

// ---------------- kernel W: weight transpose + f16 convert ----------------
// W2F fragment-linear: [e][kstep 0..7][ntile 0..15][lane 0..63][j 0..7]
//   n = ntile*16 + (lane&15), k = kstep*32 + (lane>>4)*8 + j.
__global__ __launch_bounds__(256) void kw(
    const float* __restrict__ w1, const float* __restrict__ w2,
    const float* __restrict__ o1, const float* __restrict__ o2, const float* __restrict__ o3,
    unsigned short* __restrict__ W1T, unsigned short* __restrict__ W2F,
    unsigned short* __restrict__ O1T, unsigned short* __restrict__ O2T,
    unsigned short* __restrict__ O3T) {
  int i = blockIdx.x * 256 + threadIdx.x;
  if (i < 98304) {
    int k = i & 63, n = (i >> 6) & 255, eh = i >> 14;
    int e = (eh >> 1) + 1, half = eh & 1;
    W1T[i] = f2h(w1[(e * 128 + half * 64 + k) * 256 + n]);
    return;
  }
  i -= 98304;
  if (i < 196608) {
    int j = i & 7, l = (i >> 3) & 63, t = (i >> 9) & 15, s = (i >> 13) & 7, e = i >> 16;
    int n = t * 16 + (l & 15);
    int k = s * 32 + (l >> 4) * 8 + j;
    W2F[i] = f2h(w2[(e + 1) * 65536 + k * 256 + n]);
    return;
  }
  i -= 196608;
  if (i < 81920) {
    int k = i % 320, n = i / 320;
    O1T[i] = f2h(o1[k * 256 + n]);
    return;
  }
  i -= 81920;
  if (i < 65536) {
    int k = i & 255, n = i >> 8;
    O2T[i] = f2h(o2[k * 256 + n]);
    return;
  }
  i -= 65536;
  {
    int k = i & 255, n = i >> 8;
    O3T[i] = f2h(o3[k * 64 + n]);
  }
}

// ---------------- kernel A: per-atom projections P + gates G ----------------
__global__ __launch_bounds__(256) void ka(
    const float* __restrict__ inputs, const float* __restrict__ state,
    const float* __restrict__ rel_type, const unsigned short* __restrict__ W1T,
    const float* __restrict__ b1g,
    unsigned short* __restrict__ P, float* __restrict__ G) {
  int t = blockIdx.x, b = blockIdx.y;
  int bt = b * 63 + t;
  int tid = threadIdx.x, lane = tid & 63, wid = tid >> 6;
  int waveM = wid & 1, waveN = wid >> 1;
  __shared__ __align__(16) _Float16 xa[32 * 72];
  __shared__ __align__(16) _Float16 Bt[256 * 72];
  __shared__ __align__(16) _Float16 Ps[32 * 256];
  __shared__ float ss[32][4];
  {
    int a = tid >> 3, d0 = (tid & 7) * 8;
    const float* src = inputs + (((b * 32 + a) * 64 + t) << 6) + d0;
    float4 v0 = *(const float4*)src;
    float4 v1 = *(const float4*)(src + 4);
    uint4 w;
    w.x = pkh(v0.x, v0.y); w.y = pkh(v0.z, v0.w);
    w.z = pkh(v1.x, v1.y); w.w = pkh(v1.z, v1.w);
    *(uint4*)&xa[a * 72 + d0] = w;
  }
  if (tid < 128) {
    int a = tid >> 2, s = tid & 3;
    ss[a][s] = state[((b * 32 + a) * 64 + t) * 4 + s];
  }
  __syncthreads();
  #pragma unroll
  for (int q = 0; q < 12; ++q) {
    int task = tid + q * 256;
    int e = task >> 10, rem = task & 1023, a = rem >> 5, k = rem & 31;
    float g = 0.f;
    if (k < 31) {
      int sA = k + (k >= a ? 1 : 0);
      int r = a * 31 + k;
      const float* rt = rel_type + (b * 992 + r) * 16 + (e + 1);
      g = rt[0] * ss[sA][0] + rt[4] * ss[sA][1] + rt[8] * ss[sA][2] + rt[12] * ss[sA][3];
    }
    G[(bt * 3 + e) * 1024 + a * 32 + k] = g;
  }
  for (int eh = 0; eh < 6; ++eh) {
    #pragma unroll
    for (int q = 0; q < 8; ++q) {
      int cid = tid + q * 256;
      int n = cid >> 3, c8 = (cid & 7) * 8;
      *(uint4*)&Bt[n * 72 + c8] = *(const uint4*)&W1T[(eh * 256 + n) * 64 + c8];
    }
    __syncthreads();
    f32x4 acc[8];
    #pragma unroll
    for (int f = 0; f < 8; ++f) acc[f] = f32x4{0.f, 0.f, 0.f, 0.f};
    #pragma unroll
    for (int ik = 0; ik < 2; ++ik) {
      int k0 = ik * 32;
      f16x8 av = *(const f16x8*)&xa[(waveM * 16 + (lane & 15)) * 72 + k0 + (lane >> 4) * 8];
      #pragma unroll
      for (int f = 0; f < 8; ++f) {
        f16x8 bv = *(const f16x8*)&Bt[(waveN * 128 + f * 16 + (lane & 15)) * 72 + k0 + (lane >> 4) * 8];
        acc[f] = MFMAH(av, bv, acc[f]);
      }
    }
    #pragma unroll
    for (int f = 0; f < 8; ++f) {
      int c = waveN * 128 + f * 16 + (lane & 15);
      float bias = (eh & 1) ? b1g[((eh >> 1) + 1) * 256 + c] : 0.f;
      #pragma unroll
      for (int i = 0; i < 4; ++i) {
        int rrow = waveM * 16 + (lane >> 4) * 4 + i;
        Ps[rrow * 256 + c] = (_Float16)(acc[f][i] + bias);
      }
    }
    __syncthreads();
    unsigned short* dst = P + (bt * 6 + eh) * 8192;
    #pragma unroll
    for (int q = 0; q < 4; ++q) {
      int o = (tid + q * 256) * 8;
      *(uint4*)&dst[o] = *(const uint4*)&Ps[o];
    }
    __syncthreads();
  }
}

// ---------------- kernel B v18: 3-slot counted-vmcnt ring, 2 blocks/CU ------
// grid.x = 6048 = 8*756; swz: q fastest, then bt, then e (v8 mapping).
__global__ __launch_bounds__(512, 4) void kb(
    const unsigned short* __restrict__ P, const float* __restrict__ G,
    const unsigned short* __restrict__ W2F, const float* __restrict__ b2g,
    unsigned short* __restrict__ AGG3) {
  int bx = blockIdx.x;
  int swz = (bx & 7) * 756 + (bx >> 3);
  int e = swz / 2016;
  int rem = swz - e * 2016;
  int bt = rem >> 3, q = rem & 7;
  int a0 = q * 4;
  int tid = threadIdx.x, lane = tid & 63, wid = tid >> 6;
  int waveM = wid & 1, waveN = wid >> 1;   // 2M x 4N
  int lane15 = lane & 15, kqh = lane >> 4; // 0..3

  __shared__ __align__(16) _Float16 h1F[2][4096];  // frag-linear dbuf, 16KB
  __shared__ __align__(16) _Float16 Bt[3][8192];   // frag-linear 3-slot ring, 48KB
  __shared__ float gs[128];
  __shared__ float b2s[256];
  // LDS total: 16384 + 49152 + 512 + 1024 = 67072B -> 2 blocks/CU.

  const unsigned short* psrc  = P + (bt * 6 + e * 2) * 8192;  // PS slab (send)
  const unsigned short* prsrc = psrc + 8192;                   // PRb slab
  const unsigned short* w2f   = W2F + e * 65536;               // [step][ntile][lane][8]

  // v17 build mapping: wave w builds h1 tile w, lane-linear write (0 conflicts).
  // lane l -> row w*16+(l&15), k-chunk (l>>4)*8.
  int rrow = wid * 16 + lane15;
  int al0 = rrow >> 5, bk = rrow & 31;   // atom-in-item, edge slot
  int bs = (bk < 31) ? bk + (bk >= a0 + al0 ? 1 : 0) : 0;  // k=31 pad (g=0)
  const unsigned short* pvg = psrc + bs * 256 + kqh * 8;
  const unsigned short* rvg = prsrc + (a0 + al0) * 256 + kqh * 8;
  int h1off = wid * 512 + lane * 8;

  // ---- prologue: stage Bt slots 0,1; gates/bias; build h1(0) ----
  {
    f16x8 pv = *(const f16x8*)(pvg);
    f16x8 rv = *(const f16x8*)(rvg);
    __builtin_amdgcn_sched_barrier(0);   // pv/rv issue before the gl16s
    #pragma unroll
    for (int j = 0; j < 2; ++j) {
      int c = j * 512 + tid;
      gl16(w2f + c * 8, (char*)&Bt[0][0] + c * 16);
      gl16(w2f + 8192 + c * 8, (char*)&Bt[1][0] + c * 16);
    }
    if (tid < 128) gs[tid] = G[((bt * 3 + e) << 10) + a0 * 32 + tid];
    if (tid >= 256) b2s[tid - 256] = b2g[(e + 1) * 256 + (tid - 256)];
    f16x8 h = pv + rv;
    *(f16x8*)&h1F[0][h1off] = __builtin_elementwise_max(h, h * (_Float16)0.01f);
  }
  KBAR0();  // Bt[0],Bt[1] + h1(0) + gs/b2s ready (full drain, once)

  f32x4 acc[4][4];
  #pragma unroll
  for (int f = 0; f < 4; ++f)
    #pragma unroll
    for (int g2 = 0; g2 < 4; ++g2) acc[f][g2] = f32x4{0.f, 0.f, 0.f, 0.f};

  #pragma unroll
  for (int s = 0; s < 8; ++s) {
    const int buf = s & 1;
    // issue next h1 P loads FIRST (so the compiler's wait before the ds_write
    // counts the 2 newer gl16s -> vmcnt(2), never a full drain)
    f16x8 pv, rv;
    if (s < 7) {
      pv = *(const f16x8*)(pvg + (s + 1) * 32);
      rv = *(const f16x8*)(rvg + (s + 1) * 32);
    }
    __builtin_amdgcn_sched_barrier(0);
    // stage Bt for step s+2 into ring slot (s+2)%3 — consumed two steps later
    if (s < 6) {
      #pragma unroll
      for (int j = 0; j < 2; ++j) {
        int c = j * 512 + tid;
        gl16(w2f + (s + 2) * 8192 + c * 8, (char*)&Bt[(s + 2) % 3][0] + c * 16);
      }
    }
    // MFMA on h1F[buf] x Bt[s%3] — all stride-1 fragment reads
    f16x8 af[4];
    #pragma unroll
    for (int f = 0; f < 4; ++f)
      af[f] = *(const f16x8*)&h1F[buf][(waveM * 4 + f) * 512 + lane * 8];
    __builtin_amdgcn_s_setprio(1);
    #pragma unroll
    for (int g2 = 0; g2 < 4; ++g2) {
      f16x8 bv = *(const f16x8*)&Bt[s % 3][(waveN * 4 + g2) * 512 + lane * 8];
      #pragma unroll
      for (int f = 0; f < 4; ++f)
        acc[f][g2] = MFMAH(af[f], bv, acc[f][g2]);
    }
    __builtin_amdgcn_s_setprio(0);
    if (s < 7) {
      // build h1(s+1): compiler waits vmcnt(2) here (pv/rv needed; 2 gl16 newer)
      f16x8 h = pv + rv;
      *(f16x8*)&h1F[buf ^ 1][h1off] = __builtin_elementwise_max(h, h * (_Float16)0.01f);
      if (s < 6)
        asm volatile("s_waitcnt vmcnt(2)" ::: "memory");  // Bt(s+1) stage done; s+2 in flight
      KBARL();  // lgkm-only: h1 dbuf + Bt slot handoff
    }
  }

  // epilogue: p(al,c) = sum_k g[k]*lrelu(acc+b2); write f16 partial per type
  _Float16* aggh = (_Float16*)AGG3;
  #pragma unroll
  for (int half = 0; half < 2; ++half) {
    int al = waveM * 2 + half;
    #pragma unroll
    for (int g2 = 0; g2 < 4; ++g2) {
      int c = waveN * 64 + g2 * 16 + lane15;
      float bb = b2s[c];
      float p = 0.f;
      #pragma unroll
      for (int fh = 0; fh < 2; ++fh) {
        int f = half * 2 + fh;
        int k4 = fh * 16 + kqh * 4;
        #pragma unroll
        for (int i = 0; i < 4; ++i)
          p += gs[al * 32 + k4 + i] * lrelu(acc[f][g2][i] + bb);
      }
      p += __shfl_xor(p, 16, 64);
      p += __shfl_xor(p, 32, 64);
      if (lane < 16)
        aggh[(size_t)e * 2064384 + (((bt * 32 + a0 + al) << 8) + c)] = (_Float16)p;
    }
  }
}

// ---------------- kernel C: output MLP 320->256->256->64 + residual ----------------
__global__ __launch_bounds__(256) void kc(
    const float* __restrict__ inputs, const unsigned short* __restrict__ AGG3,
    const unsigned short* __restrict__ O1T, const unsigned short* __restrict__ O2T,
    const unsigned short* __restrict__ O3T,
    const float* __restrict__ ob1, const float* __restrict__ ob2, const float* __restrict__ ob3,
    float* __restrict__ out) {
  int t = blockIdx.x, b = blockIdx.y;
  int bt = b * 63 + t;
  int tid = threadIdx.x, lane = tid & 63, wid = tid >> 6;
  int waveM = wid & 1, waveN = wid >> 1;
  __shared__ __align__(16) _Float16 aug[32 * 328];
  __shared__ __align__(16) _Float16 h1[32 * 264];
  __shared__ __align__(16) _Float16 h2[32 * 264];
  __shared__ __align__(16) _Float16 Bt[256 * 40];
  __shared__ __align__(16) float xs[32 * 64];
  __shared__ float lb1[256], lb2[256], lb3[64];
  {
    int a = tid >> 3, d0 = (tid & 7) * 8;
    const float* src = inputs + (((b * 32 + a) * 64 + t) << 6) + d0;
    float4 v0 = *(const float4*)src;
    float4 v1 = *(const float4*)(src + 4);
    *(float4*)&xs[a * 64 + d0] = v0;
    *(float4*)&xs[a * 64 + d0 + 4] = v1;
    uint4 w;
    w.x = pkh(v0.x, v0.y); w.y = pkh(v0.z, v0.w);
    w.z = pkh(v1.x, v1.y); w.w = pkh(v1.z, v1.w);
    *(uint4*)&aug[a * 328 + d0] = w;
  }
  #pragma unroll
  for (int qq = 0; qq < 4; ++qq) {
    int cid = tid + qq * 256;
    int a = cid >> 5, c8 = (cid & 31) * 8;
    size_t o = ((size_t)(bt * 32 + a) << 8) + c8;
    f16x8 v0 = *(const f16x8*)&AGG3[o];
    f16x8 v1 = *(const f16x8*)&AGG3[2064384 + o];
    f16x8 v2 = *(const f16x8*)&AGG3[4128768 + o];
    f16x8 s = v0 + v1 + v2;
    *(uint4*)&aug[a * 328 + 64 + c8] = __builtin_bit_cast(uint4, s);
  }
  lb1[tid] = ob1[tid];
  lb2[tid] = ob2[tid];
  if (tid < 64) lb3[tid] = ob3[tid];
  __syncthreads();
  f32x4 acc[8];
  #pragma unroll
  for (int f = 0; f < 8; ++f) acc[f] = f32x4{0.f, 0.f, 0.f, 0.f};
  for (int kk = 0; kk < 10; ++kk) {  // fc1: K=320
    #pragma unroll
    for (int q = 0; q < 4; ++q) {
      int cid = tid + q * 256;
      int n = cid >> 2, c8 = (cid & 3) * 8;
      *(uint4*)&Bt[n * 40 + c8] = *(const uint4*)&O1T[n * 320 + kk * 32 + c8];
    }
    __syncthreads();
    f16x8 av = *(const f16x8*)&aug[(waveM * 16 + (lane & 15)) * 328 + kk * 32 + (lane >> 4) * 8];
    #pragma unroll
    for (int f = 0; f < 8; ++f) {
      f16x8 bv = *(const f16x8*)&Bt[(waveN * 128 + f * 16 + (lane & 15)) * 40 + (lane >> 4) * 8];
      acc[f] = MFMAH(av, bv, acc[f]);
    }
    __syncthreads();
  }
  #pragma unroll
  for (int f = 0; f < 8; ++f) {
    int c = waveN * 128 + f * 16 + (lane & 15);
    #pragma unroll
    for (int i = 0; i < 4; ++i) {
      int r = waveM * 16 + (lane >> 4) * 4 + i;
      h1[r * 264 + c] = (_Float16)lrelu(acc[f][i] + lb1[c]);
    }
  }
  __syncthreads();
  #pragma unroll
  for (int f = 0; f < 8; ++f) acc[f] = f32x4{0.f, 0.f, 0.f, 0.f};
  for (int kk = 0; kk < 8; ++kk) {  // fc2: K=256
    #pragma unroll
    for (int q = 0; q < 4; ++q) {
      int cid = tid + q * 256;
      int n = cid >> 2, c8 = (cid & 3) * 8;
      *(uint4*)&Bt[n * 40 + c8] = *(const uint4*)&O2T[n * 256 + kk * 32 + c8];
    }
    __syncthreads();
    f16x8 av = *(const f16x8*)&h1[(waveM * 16 + (lane & 15)) * 264 + kk * 32 + (lane >> 4) * 8];
    #pragma unroll
    for (int f = 0; f < 8; ++f) {
      f16x8 bv = *(const f16x8*)&Bt[(waveN * 128 + f * 16 + (lane & 15)) * 40 + (lane >> 4) * 8];
      acc[f] = MFMAH(av, bv, acc[f]);
    }
    __syncthreads();
  }
  #pragma unroll
  for (int f = 0; f < 8; ++f) {
    int c = waveN * 128 + f * 16 + (lane & 15);
    #pragma unroll
    for (int i = 0; i < 4; ++i) {
      int r = waveM * 16 + (lane >> 4) * 4 + i;
      h2[r * 264 + c] = (_Float16)lrelu(acc[f][i] + lb2[c]);
    }
  }
  __syncthreads();
  f32x4 a3[2];
  a3[0] = f32x4{0.f, 0.f, 0.f, 0.f};
  a3[1] = f32x4{0.f, 0.f, 0.f, 0.f};
  for (int kk = 0; kk < 8; ++kk) {  // fc3: K=256, N=64
    {
      int n = tid >> 2, c8 = (tid & 3) * 8;
      *(uint4*)&Bt[n * 40 + c8] = *(const uint4*)&O3T[n * 256 + kk * 32 + c8];
    }
    __syncthreads();
    f16x8 av = *(const f16x8*)&h2[(waveM * 16 + (lane & 15)) * 264 + kk * 32 + (lane >> 4) * 8];
    #pragma unroll
    for (int f = 0; f < 2; ++f) {
      f16x8 bv = *(const f16x8*)&Bt[(waveN * 32 + f * 16 + (lane & 15)) * 40 + (lane >> 4) * 8];
      a3[f] = MFMAH(av, bv, a3[f]);
    }
    __syncthreads();
  }
  #pragma unroll
  for (int f = 0; f < 2; ++f) {
    int d = waveN * 32 + f * 16 + (lane & 15);
    #pragma unroll
    for (int i = 0; i < 4; ++i) {
      int a = waveM * 16 + (lane >> 4) * 4 + i;
      out[((b * 32 + a) * 63 + t) * 64 + d] = a3[f][i] + lb3[d] + xs[a * 64 + d];
    }
  }
}

extern "C" void kernel_launch(void* const* d_in, const int* in_sizes, int n_in,
                              void* d_out, int out_size, void* d_ws, size_t ws_size,
                              hipStream_t stream) {
  const float* inputs   = (const float*)d_in[0];
  const float* state    = (const float*)d_in[1];
  const float* rel_type = (const float*)d_in[2];
  const float* w1  = (const float*)d_in[5];
  const float* b1  = (const float*)d_in[6];
  const float* w2  = (const float*)d_in[7];
  const float* b2  = (const float*)d_in[8];
  const float* o1w = (const float*)d_in[9];
  const float* o1b = (const float*)d_in[10];
  const float* o2w = (const float*)d_in[11];
  const float* o2b = (const float*)d_in[12];
  const float* o3w = (const float*)d_in[13];
  const float* o3b = (const float*)d_in[14];
  char* ws = (char*)d_ws;
  unsigned short* W1T = (unsigned short*)(ws + 0);
  unsigned short* W2F = (unsigned short*)(ws + 196608);     // 393216 B (frag-linear)
  unsigned short* O1T = (unsigned short*)(ws + 589824);
  unsigned short* O2T = (unsigned short*)(ws + 753664);
  unsigned short* O3T = (unsigned short*)(ws + 884736);
  unsigned short* Pp  = (unsigned short*)(ws + 917504);     // 24772608 B
  float* G    = (float*)(ws + 25690112);                    // 3096576 B
  unsigned short* AGG3 = (unsigned short*)(ws + 28786688);  // 12386304 B
  float* out = (float*)d_out;

  kw<<<1792, 256, 0, stream>>>(w1, w2, o1w, o2w, o3w, W1T, W2F, O1T, O2T, O3T);
  ka<<<dim3(63, 4), 256, 0, stream>>>(inputs, state, rel_type, W1T, b1, Pp, G);
  kb<<<6048, 512, 0, stream>>>(Pp, G, W2F, b2, AGG3);
  kc<<<dim3(63, 4), 256, 0, stream>>>(inputs, AGG3, O1T, O2T, O3T, o1b, o2b, o3b, out);
}